// Round 1
// baseline (421.710 us; speedup 1.0000x reference)
//
#include <hip/hip_runtime.h>
#include <hip/hip_bf16.h>

// Problem constants (match setup_inputs / reference)
constexpr int B = 2, C = 256, H = 160, W = 160;
constexpr int K = 64;
constexpr int PH = 64, PW = 64;   // POOLED_H/W
constexpr int SR = 2;
constexpr float SCALE_X = (float)W / 640.0f;  // 0.25
constexpr float SCALE_Y = (float)H / 640.0f;  // 0.25

// One block handles one (k, ph) output row across all channels.
// blockDim = (64, 4): threadIdx.x = pw (coalesced store lane),
// threadIdx.y = channel phase; each thread loops c += 4.
__global__ __launch_bounds__(256) void roi_align_kernel(
    const float* __restrict__ images,   // [B, C, H, W]
    const float* __restrict__ rois,     // [K, 5]
    float* __restrict__ out)            // [K, C, PH, PW]
{
    const int k  = blockIdx.x >> 6;     // 0..K-1
    const int ph = blockIdx.x & 63;     // 0..PH-1
    const int pw = threadIdx.x;         // 0..63
    const int c0 = threadIdx.y;         // 0..3

    const float* box = rois + k * 5;
    const int   b   = (int)box[0];
    const float bx1 = box[1] * SCALE_X - 0.5f;
    const float by1 = box[2] * SCALE_Y - 0.5f;
    const float bx2 = box[3] * SCALE_X - 0.5f;
    const float by2 = box[4] * SCALE_Y - 0.5f;
    const float bin_w = (bx2 - bx1) * (1.0f / PW);
    const float bin_h = (by2 - by1) * (1.0f / PH);

    // y samples for this ph (2 of them), shared by all lanes
    int   y0i[SR], y1i[SR];
    float ly[SR], hy[SR];
    bool  vy[SR];
#pragma unroll
    for (int iy = 0; iy < SR; ++iy) {
        float g = ((float)(ph * SR + iy) + 0.5f) * (1.0f / SR);
        float y = by1 + g * bin_h;
        vy[iy] = (y >= -1.0f) && (y <= (float)H);
        float yc = fminf(fmaxf(y, 0.0f), (float)(H - 1));
        int   yy = (int)floorf(yc);
        y0i[iy] = yy;
        y1i[iy] = min(yy + 1, H - 1);
        ly[iy]  = yc - (float)yy;
        hy[iy]  = 1.0f - ly[iy];
    }

    // x samples for this pw (2 of them)
    int   x0i[SR], x1i[SR];
    float lx[SR], hx[SR];
    bool  vx[SR];
#pragma unroll
    for (int ix = 0; ix < SR; ++ix) {
        float g = ((float)(pw * SR + ix) + 0.5f) * (1.0f / SR);
        float x = bx1 + g * bin_w;
        vx[ix] = (x >= -1.0f) && (x <= (float)W);
        float xc = fminf(fmaxf(x, 0.0f), (float)(W - 1));
        int   xx = (int)floorf(xc);
        x0i[ix] = xx;
        x1i[ix] = min(xx + 1, W - 1);
        lx[ix]  = xc - (float)xx;
        hx[ix]  = 1.0f - lx[ix];
    }

    // Precompute 16 tap offsets + weights (mask + 1/4 mean folded in).
    int   off[16];
    float wgt[16];
#pragma unroll
    for (int iy = 0; iy < SR; ++iy) {
#pragma unroll
        for (int ix = 0; ix < SR; ++ix) {
            const float v = (vy[iy] && vx[ix]) ? 0.25f : 0.0f;
            const int t = (iy * SR + ix) * 4;
            off[t + 0] = y0i[iy] * W + x0i[ix];
            off[t + 1] = y0i[iy] * W + x1i[ix];
            off[t + 2] = y1i[iy] * W + x0i[ix];
            off[t + 3] = y1i[iy] * W + x1i[ix];
            wgt[t + 0] = hy[iy] * hx[ix] * v;
            wgt[t + 1] = hy[iy] * lx[ix] * v;
            wgt[t + 2] = ly[iy] * hx[ix] * v;
            wgt[t + 3] = ly[iy] * lx[ix] * v;
        }
    }

    const float* img  = images + (size_t)b * C * H * W;
    float*       outk = out + ((size_t)k * C) * (PH * PW) + ph * PW + pw;

#pragma unroll 2
    for (int c = c0; c < C; c += 4) {
        const float* f = img + (size_t)c * (H * W);
        float acc = 0.0f;
#pragma unroll
        for (int t = 0; t < 16; ++t) {
            acc = fmaf(wgt[t], f[off[t]], acc);
        }
        outk[(size_t)c * (PH * PW)] = acc;
    }
}

extern "C" void kernel_launch(void* const* d_in, const int* in_sizes, int n_in,
                              void* d_out, int out_size, void* d_ws, size_t ws_size,
                              hipStream_t stream) {
    const float* images = (const float*)d_in[0];
    const float* rois   = (const float*)d_in[1];
    float*       out    = (float*)d_out;

    dim3 grid(K * PH);      // 4096 blocks: one per (k, ph)
    dim3 block(PW, 4);      // 64 lanes (= pw) x 4 channel phases
    hipLaunchKernelGGL(roi_align_kernel, grid, block, 0, stream,
                       images, rois, out);
}

// Round 2
// 222.593 us; speedup vs baseline: 1.8945x; 1.8945x over previous
//
#include <hip/hip_runtime.h>
#include <hip/hip_bf16.h>

// Problem constants (match setup_inputs / reference)
constexpr int B = 2, C = 256, H = 160, W = 160;
constexpr int HW = H * W;
constexpr int K = 64;
constexpr int PH = 64, PW = 64;
constexpr int SR = 2;
constexpr float SCALE_X = (float)W / 640.0f;  // 0.25
constexpr float SCALE_Y = (float)H / 640.0f;  // 0.25

// ---------------------------------------------------------------------------
// Kernel 1: transpose images [B][C][HW] -> channels-last tl [B][HW][C]
// Tiled 64x64 through LDS; fully coalesced reads and writes.
// ---------------------------------------------------------------------------
__global__ __launch_bounds__(256) void transpose_cl(const float* __restrict__ in,
                                                    float* __restrict__ tl) {
    __shared__ float t[64][65];
    const int lane = threadIdx.x;      // 64
    const int wv   = threadIdx.y;      // 4
    const int s0 = blockIdx.x * 64;    // 400 tiles over HW
    const int c0 = blockIdx.y * 64;    // 4 tiles over C
    const int b  = blockIdx.z;         // 2

    const float* src = in + ((size_t)b * C + c0) * HW + s0;
#pragma unroll
    for (int r = 0; r < 16; ++r) {
        const int cl = wv * 16 + r;                 // local channel row
        t[cl][lane] = src[(size_t)cl * HW + lane];  // coalesced over lane
    }
    __syncthreads();
    float* dst = tl + ((size_t)b * HW + s0) * C + c0;
#pragma unroll
    for (int r = 0; r < 16; ++r) {
        const int sl = wv * 16 + r;                 // local spatial row
        dst[(size_t)sl * C + lane] = t[lane][sl];   // coalesced over lane
    }
}

// ---------------------------------------------------------------------------
// Kernel 2: ROI align on channels-last features.
// Block = one (k, ph). lane = channel quad (4*lane..4*lane+3), wv = pw phase.
// Each bilinear tap: one coalesced 1KB wave load (float4 x 64 lanes = all C).
// Output transposed back to [K][C][PH][PW] through LDS (32-pw chunks).
// ---------------------------------------------------------------------------
__global__ __launch_bounds__(256) void roi_align_cl(const float* __restrict__ tl,
                                                    const float* __restrict__ rois,
                                                    float* __restrict__ out) {
    __shared__ float sm[32 * 260];     // [pw32][C + pad(4)] ; 33.3 KB

    const int k  = blockIdx.x >> 6;
    const int ph = blockIdx.x & 63;
    const int lane = threadIdx.x;      // 64: channel quad index
    const int wv   = threadIdx.y;      // 4
    const int cq   = lane * 4;

    const float* box = rois + k * 5;
    const int   b   = (int)box[0];
    const float bx1 = box[1] * SCALE_X - 0.5f;
    const float by1 = box[2] * SCALE_Y - 0.5f;
    const float bx2 = box[3] * SCALE_X - 0.5f;
    const float by2 = box[4] * SCALE_Y - 0.5f;
    const float bin_w = (bx2 - bx1) * (1.0f / PW);
    const float bin_h = (by2 - by1) * (1.0f / PH);

    // Two y samples for this ph; rows uniform across the block.
    const float* rowp[2][2];
    float wy[2][2];
    bool  vy[2];
#pragma unroll
    for (int iy = 0; iy < 2; ++iy) {
        const float y = by1 + ((float)(ph * SR + iy) + 0.5f) * (1.0f / SR) * bin_h;
        vy[iy] = (y >= -1.0f) && (y <= (float)H);
        const float yc = fminf(fmaxf(y, 0.0f), (float)(H - 1));
        const int y0 = (int)floorf(yc);
        const int y1 = min(y0 + 1, H - 1);
        const float ly = yc - (float)y0;
        wy[iy][0] = 1.0f - ly;
        wy[iy][1] = ly;
        rowp[iy][0] = tl + ((size_t)b * HW + (size_t)y0 * W) * C;
        rowp[iy][1] = tl + ((size_t)b * HW + (size_t)y1 * W) * C;
    }

    for (int chunk = 0; chunk < 2; ++chunk) {
#pragma unroll 2
        for (int i = 0; i < 8; ++i) {
            const int pwi = wv * 8 + i;            // 0..31 within chunk
            const int pw  = chunk * 32 + pwi;
            float4 acc = make_float4(0.f, 0.f, 0.f, 0.f);
#pragma unroll
            for (int ix = 0; ix < 2; ++ix) {
                const float x = bx1 + ((float)(pw * SR + ix) + 0.5f) * (1.0f / SR) * bin_w;
                const bool vx = (x >= -1.0f) && (x <= (float)W);
                const float xc = fminf(fmaxf(x, 0.0f), (float)(W - 1));
                const int x0 = (int)floorf(xc);
                const int x1 = min(x0 + 1, W - 1);
                const float lx  = xc - (float)x0;
                const float wx0 = 1.0f - lx;
                const float wx1 = lx;
#pragma unroll
                for (int iy = 0; iy < 2; ++iy) {
                    const float vs  = (vy[iy] && vx) ? 0.25f : 0.0f;
                    const float w00 = wy[iy][0] * wx0 * vs;
                    const float w01 = wy[iy][0] * wx1 * vs;
                    const float w10 = wy[iy][1] * wx0 * vs;
                    const float w11 = wy[iy][1] * wx1 * vs;
                    const float4 f00 = *(const float4*)(rowp[iy][0] + (size_t)x0 * C + cq);
                    const float4 f01 = *(const float4*)(rowp[iy][0] + (size_t)x1 * C + cq);
                    const float4 f10 = *(const float4*)(rowp[iy][1] + (size_t)x0 * C + cq);
                    const float4 f11 = *(const float4*)(rowp[iy][1] + (size_t)x1 * C + cq);
                    acc.x = fmaf(w00, f00.x, acc.x); acc.y = fmaf(w00, f00.y, acc.y);
                    acc.z = fmaf(w00, f00.z, acc.z); acc.w = fmaf(w00, f00.w, acc.w);
                    acc.x = fmaf(w01, f01.x, acc.x); acc.y = fmaf(w01, f01.y, acc.y);
                    acc.z = fmaf(w01, f01.z, acc.z); acc.w = fmaf(w01, f01.w, acc.w);
                    acc.x = fmaf(w10, f10.x, acc.x); acc.y = fmaf(w10, f10.y, acc.y);
                    acc.z = fmaf(w10, f10.z, acc.z); acc.w = fmaf(w10, f10.w, acc.w);
                    acc.x = fmaf(w11, f11.x, acc.x); acc.y = fmaf(w11, f11.y, acc.y);
                    acc.z = fmaf(w11, f11.z, acc.z); acc.w = fmaf(w11, f11.w, acc.w);
                }
            }
            // b128 write: pwi uniform across wave, lanes contiguous -> conflict-free
            *(float4*)(&sm[pwi * 260 + cq]) = acc;
        }
        __syncthreads();
        // Store phase: each wave-instr writes 2 channel rows x 32 contiguous pw.
#pragma unroll
        for (int it = 0; it < 32; ++it) {
            const int c   = it * 8 + wv * 2 + (lane >> 5);
            const int pwi = lane & 31;
            out[((size_t)k * C + c) * (PH * PW) + ph * PW + chunk * 32 + pwi] =
                sm[pwi * 260 + c];
        }
        __syncthreads();
    }
}

// ---------------------------------------------------------------------------
// Fallback (round-1 kernel) if workspace is too small for the transposed copy.
// ---------------------------------------------------------------------------
__global__ __launch_bounds__(256) void roi_align_fallback(
    const float* __restrict__ images, const float* __restrict__ rois,
    float* __restrict__ out) {
    const int k  = blockIdx.x >> 6;
    const int ph = blockIdx.x & 63;
    const int pw = threadIdx.x;
    const int c0 = threadIdx.y;

    const float* box = rois + k * 5;
    const int   b   = (int)box[0];
    const float bx1 = box[1] * SCALE_X - 0.5f;
    const float by1 = box[2] * SCALE_Y - 0.5f;
    const float bx2 = box[3] * SCALE_X - 0.5f;
    const float by2 = box[4] * SCALE_Y - 0.5f;
    const float bin_w = (bx2 - bx1) * (1.0f / PW);
    const float bin_h = (by2 - by1) * (1.0f / PH);

    int y0i[SR], y1i[SR]; float ly[SR], hy[SR]; bool vyv[SR];
#pragma unroll
    for (int iy = 0; iy < SR; ++iy) {
        float g = ((float)(ph * SR + iy) + 0.5f) * (1.0f / SR);
        float y = by1 + g * bin_h;
        vyv[iy] = (y >= -1.0f) && (y <= (float)H);
        float yc = fminf(fmaxf(y, 0.0f), (float)(H - 1));
        int yy = (int)floorf(yc);
        y0i[iy] = yy; y1i[iy] = min(yy + 1, H - 1);
        ly[iy] = yc - (float)yy; hy[iy] = 1.0f - ly[iy];
    }
    int x0i[SR], x1i[SR]; float lx[SR], hx[SR]; bool vxv[SR];
#pragma unroll
    for (int ix = 0; ix < SR; ++ix) {
        float g = ((float)(pw * SR + ix) + 0.5f) * (1.0f / SR);
        float x = bx1 + g * bin_w;
        vxv[ix] = (x >= -1.0f) && (x <= (float)W);
        float xc = fminf(fmaxf(x, 0.0f), (float)(W - 1));
        int xx = (int)floorf(xc);
        x0i[ix] = xx; x1i[ix] = min(xx + 1, W - 1);
        lx[ix] = xc - (float)xx; hx[ix] = 1.0f - lx[ix];
    }
    int off[16]; float wgt[16];
#pragma unroll
    for (int iy = 0; iy < SR; ++iy) {
#pragma unroll
        for (int ix = 0; ix < SR; ++ix) {
            const float v = (vyv[iy] && vxv[ix]) ? 0.25f : 0.0f;
            const int t = (iy * SR + ix) * 4;
            off[t + 0] = y0i[iy] * W + x0i[ix];
            off[t + 1] = y0i[iy] * W + x1i[ix];
            off[t + 2] = y1i[iy] * W + x0i[ix];
            off[t + 3] = y1i[iy] * W + x1i[ix];
            wgt[t + 0] = hy[iy] * hx[ix] * v;
            wgt[t + 1] = hy[iy] * lx[ix] * v;
            wgt[t + 2] = ly[iy] * hx[ix] * v;
            wgt[t + 3] = ly[iy] * lx[ix] * v;
        }
    }
    const float* img  = images + (size_t)b * C * HW;
    float*       outk = out + ((size_t)k * C) * (PH * PW) + ph * PW + pw;
#pragma unroll 2
    for (int c = c0; c < C; c += 4) {
        const float* f = img + (size_t)c * HW;
        float acc = 0.0f;
#pragma unroll
        for (int t = 0; t < 16; ++t) acc = fmaf(wgt[t], f[off[t]], acc);
        outk[(size_t)c * (PH * PW)] = acc;
    }
}

extern "C" void kernel_launch(void* const* d_in, const int* in_sizes, int n_in,
                              void* d_out, int out_size, void* d_ws, size_t ws_size,
                              hipStream_t stream) {
    const float* images = (const float*)d_in[0];
    const float* rois   = (const float*)d_in[1];
    float*       out    = (float*)d_out;

    const size_t tl_bytes = (size_t)B * HW * C * sizeof(float);  // 52.4 MB
    if (ws_size >= tl_bytes) {
        float* tl = (float*)d_ws;
        dim3 tgrid(HW / 64, C / 64, B);   // 400 x 4 x 2
        dim3 tblock(64, 4);
        hipLaunchKernelGGL(transpose_cl, tgrid, tblock, 0, stream, images, tl);

        dim3 grid(K * PH);                // 4096
        dim3 block(64, 4);
        hipLaunchKernelGGL(roi_align_cl, grid, block, 0, stream, tl, rois, out);
    } else {
        dim3 grid(K * PH);
        dim3 block(PW, 4);
        hipLaunchKernelGGL(roi_align_fallback, grid, block, 0, stream,
                           images, rois, out);
    }
}

// Round 3
// 136.840 us; speedup vs baseline: 3.0818x; 1.6267x over previous
//
#include <hip/hip_runtime.h>
#include <hip/hip_bf16.h>

// Problem constants (match setup_inputs / reference)
constexpr int B = 2, C = 256, H = 160, W = 160;
constexpr int HW = H * W;
constexpr int K = 64;
constexpr int PH = 64, PW = 64;
constexpr float SCALE = 0.25f;            // 160/640

constexpr int D     = 12;    // distinct x-columns per 16-pw chunk (span<=9.7px +1 tap)
constexpr int CP    = 16;    // pw per chunk
constexpr int PITCH = 260;   // LDS row pitch (floats); 260%32=4 -> 2-way reads in phase C

__device__ __forceinline__ void fma4(float4& a, float w, const float4& f) {
    a.x = fmaf(w, f.x, a.x); a.y = fmaf(w, f.y, a.y);
    a.z = fmaf(w, f.z, a.z); a.w = fmaf(w, f.w, a.w);
}

// ---------------------------------------------------------------------------
// Kernel 1: transpose images [B][C][HW] -> channels-last tl [B][HW][C]
// ---------------------------------------------------------------------------
__global__ __launch_bounds__(256) void transpose_cl(const float* __restrict__ in,
                                                    float* __restrict__ tl) {
    __shared__ float t[64][65];
    const int lane = threadIdx.x;
    const int wv   = threadIdx.y;
    const int s0 = blockIdx.x * 64;
    const int c0 = blockIdx.y * 64;
    const int b  = blockIdx.z;

    const float* src = in + ((size_t)b * C + c0) * HW + s0;
#pragma unroll
    for (int r = 0; r < 16; ++r) {
        const int cl = wv * 16 + r;
        t[cl][lane] = src[(size_t)cl * HW + lane];
    }
    __syncthreads();
    float* dst = tl + ((size_t)b * HW + s0) * C + c0;
#pragma unroll
    for (int r = 0; r < 16; ++r) {
        const int sl = wv * 16 + r;
        dst[(size_t)sl * C + lane] = t[lane][sl];
    }
}

// ---------------------------------------------------------------------------
// Kernel 2: separable ROI align on channels-last features.
// Block = one (k, ph); 4 waves. lane = channel quad (cq=lane*4).
// Per 16-pw chunk:
//   A: fold 4 y-rows (2 iy-samples x 2 taps, validity+0.5 in weights) into
//      one combined row g[12 cols][256 ch] in LDS (12 wave-loads/wave).
//   B: x-interp: 4 conflict-free b128 LDS taps per pw -> out-chunk LDS.
//   C: transpose-store: float4 along pw, coalesced 64B segments.
// ---------------------------------------------------------------------------
__global__ __launch_bounds__(256) void roi_align_sep(const float* __restrict__ tl,
                                                     const float* __restrict__ rois,
                                                     float* __restrict__ out) {
    __shared__ float g [D  * PITCH];   // 12.5 KB
    __shared__ float ob[CP * PITCH];   // 16.6 KB

    const int k    = blockIdx.x >> 6;
    const int ph   = blockIdx.x & 63;
    const int lane = threadIdx.x;      // 64
    const int wv   = threadIdx.y;      // 4
    const int cq   = lane * 4;

    const float* box = rois + k * 5;
    const int   b   = (int)box[0];
    const float bx1 = box[1] * SCALE - 0.5f;
    const float by1 = box[2] * SCALE - 0.5f;
    const float bin_w = (box[3] * SCALE - 0.5f - bx1) * (1.0f / PW);
    const float bin_h = (box[4] * SCALE - 0.5f - by1) * (1.0f / PH);

    // Combined y-row weights: 2 iy-samples x 2 taps; 0.5 (mean) + vy folded in.
    const float* rowp[4];
    float wrow[4];
#pragma unroll
    for (int iy = 0; iy < 2; ++iy) {
        const float y = by1 + ((float)(2 * ph + iy) + 0.5f) * 0.5f * bin_h;
        const float v = (y >= -1.0f && y <= (float)H) ? 0.5f : 0.0f;
        const float yc = fminf(fmaxf(y, 0.0f), (float)(H - 1));
        const int   y0 = (int)floorf(yc);
        const int   y1 = min(y0 + 1, H - 1);
        const float ly = yc - (float)y0;
        rowp[iy * 2 + 0] = tl + ((size_t)b * HW + (size_t)y0 * W) * C;
        rowp[iy * 2 + 1] = tl + ((size_t)b * HW + (size_t)y1 * W) * C;
        wrow[iy * 2 + 0] = (1.0f - ly) * v;
        wrow[iy * 2 + 1] = ly * v;
    }

    for (int chunk = 0; chunk < 4; ++chunk) {
        const int pw0 = chunk * CP;
        // xlo from the chunk's first sample (same expression as phase B -> exact)
        const float xf  = bx1 + ((float)(2 * pw0) + 0.5f) * 0.5f * bin_w;
        const int   xlo = (int)floorf(fminf(fmaxf(xf, 0.0f), (float)(W - 1)));

        // ---- Phase A: y-combine 12 columns (3 per wave) ----
#pragma unroll
        for (int jj = 0; jj < 3; ++jj) {
            const int j    = wv * 3 + jj;
            const int xcol = min(xlo + j, W - 1);
            const size_t base = (size_t)xcol * C + cq;
            const float4 f0 = *(const float4*)(rowp[0] + base);
            const float4 f1 = *(const float4*)(rowp[1] + base);
            const float4 f2 = *(const float4*)(rowp[2] + base);
            const float4 f3 = *(const float4*)(rowp[3] + base);
            float4 a = make_float4(0.f, 0.f, 0.f, 0.f);
            fma4(a, wrow[0], f0); fma4(a, wrow[1], f1);
            fma4(a, wrow[2], f2); fma4(a, wrow[3], f3);
            *(float4*)&g[j * PITCH + cq] = a;   // contiguous wave write
        }
        __syncthreads();

        // ---- Phase B: x-interp, 4 pw per wave ----
#pragma unroll
        for (int i = 0; i < 4; ++i) {
            const int pw = pw0 + wv * 4 + i;
            float4 acc = make_float4(0.f, 0.f, 0.f, 0.f);
#pragma unroll
            for (int ix = 0; ix < 2; ++ix) {
                const float x  = bx1 + ((float)(2 * pw + ix) + 0.5f) * 0.5f * bin_w;
                const float v  = (x >= -1.0f && x <= (float)W) ? 0.5f : 0.0f;
                const float xc = fminf(fmaxf(x, 0.0f), (float)(W - 1));
                const int   x0 = (int)floorf(xc);
                const float lx = xc - (float)x0;
                const int   l0 = x0 - xlo;                 // in [0, 10]
                const int   l1 = min(x0 + 1, W - 1) - xlo; // in [0, 11]
                const float w0 = (1.0f - lx) * v;
                const float w1 = lx * v;
                const float4 g0 = *(const float4*)&g[l0 * PITCH + cq];
                const float4 g1 = *(const float4*)&g[l1 * PITCH + cq];
                fma4(acc, w0, g0);
                fma4(acc, w1, g1);
            }
            *(float4*)&ob[(wv * 4 + i) * PITCH + cq] = acc;  // contiguous
        }
        __syncthreads();

        // ---- Phase C: transpose-store; float4 along pw, 2-way LDS reads ----
#pragma unroll
        for (int it = 0; it < 4; ++it) {
            const int c  = it * 64 + wv * 16 + (lane >> 2);
            const int pq = (lane & 3) * 4;
            float4 vv;
            vv.x = ob[(pq + 0) * PITCH + c];
            vv.y = ob[(pq + 1) * PITCH + c];
            vv.z = ob[(pq + 2) * PITCH + c];
            vv.w = ob[(pq + 3) * PITCH + c];
            *(float4*)&out[((size_t)k * C + c) * (PH * PW) + ph * PW + pw0 + pq] = vv;
        }
        __syncthreads();
    }
}

// ---------------------------------------------------------------------------
// Fallback (round-1 kernel) if workspace is too small for the transposed copy.
// ---------------------------------------------------------------------------
__global__ __launch_bounds__(256) void roi_align_fallback(
    const float* __restrict__ images, const float* __restrict__ rois,
    float* __restrict__ out) {
    const int k  = blockIdx.x >> 6;
    const int ph = blockIdx.x & 63;
    const int pw = threadIdx.x;
    const int c0 = threadIdx.y;

    const float* box = rois + k * 5;
    const int   b   = (int)box[0];
    const float bx1 = box[1] * SCALE - 0.5f;
    const float by1 = box[2] * SCALE - 0.5f;
    const float bin_w = (box[3] * SCALE - 0.5f - bx1) * (1.0f / PW);
    const float bin_h = (box[4] * SCALE - 0.5f - by1) * (1.0f / PH);

    int y0i[2], y1i[2]; float ly[2], hy[2]; bool vyv[2];
#pragma unroll
    for (int iy = 0; iy < 2; ++iy) {
        float y = by1 + ((float)(2 * ph + iy) + 0.5f) * 0.5f * bin_h;
        vyv[iy] = (y >= -1.0f) && (y <= (float)H);
        float yc = fminf(fmaxf(y, 0.0f), (float)(H - 1));
        int yy = (int)floorf(yc);
        y0i[iy] = yy; y1i[iy] = min(yy + 1, H - 1);
        ly[iy] = yc - (float)yy; hy[iy] = 1.0f - ly[iy];
    }
    int x0i[2], x1i[2]; float lx[2], hx[2]; bool vxv[2];
#pragma unroll
    for (int ix = 0; ix < 2; ++ix) {
        float x = bx1 + ((float)(2 * pw + ix) + 0.5f) * 0.5f * bin_w;
        vxv[ix] = (x >= -1.0f) && (x <= (float)W);
        float xc = fminf(fmaxf(x, 0.0f), (float)(W - 1));
        int xx = (int)floorf(xc);
        x0i[ix] = xx; x1i[ix] = min(xx + 1, W - 1);
        lx[ix] = xc - (float)xx; hx[ix] = 1.0f - lx[ix];
    }
    int off[16]; float wgt[16];
#pragma unroll
    for (int iy = 0; iy < 2; ++iy) {
#pragma unroll
        for (int ix = 0; ix < 2; ++ix) {
            const float v = (vyv[iy] && vxv[ix]) ? 0.25f : 0.0f;
            const int t = (iy * 2 + ix) * 4;
            off[t + 0] = y0i[iy] * W + x0i[ix];
            off[t + 1] = y0i[iy] * W + x1i[ix];
            off[t + 2] = y1i[iy] * W + x0i[ix];
            off[t + 3] = y1i[iy] * W + x1i[ix];
            wgt[t + 0] = hy[iy] * hx[ix] * v;
            wgt[t + 1] = hy[iy] * lx[ix] * v;
            wgt[t + 2] = ly[iy] * hx[ix] * v;
            wgt[t + 3] = ly[iy] * lx[ix] * v;
        }
    }
    const float* img  = images + (size_t)b * C * HW;
    float*       outk = out + ((size_t)k * C) * (PH * PW) + ph * PW + pw;
#pragma unroll 2
    for (int c = c0; c < C; c += 4) {
        const float* f = img + (size_t)c * HW;
        float acc = 0.0f;
#pragma unroll
        for (int t = 0; t < 16; ++t) acc = fmaf(wgt[t], f[off[t]], acc);
        outk[(size_t)c * (PH * PW)] = acc;
    }
}

extern "C" void kernel_launch(void* const* d_in, const int* in_sizes, int n_in,
                              void* d_out, int out_size, void* d_ws, size_t ws_size,
                              hipStream_t stream) {
    const float* images = (const float*)d_in[0];
    const float* rois   = (const float*)d_in[1];
    float*       out    = (float*)d_out;

    const size_t tl_bytes = (size_t)B * HW * C * sizeof(float);  // 52.4 MB
    if (ws_size >= tl_bytes) {
        float* tl = (float*)d_ws;
        dim3 tgrid(HW / 64, C / 64, B);
        dim3 tblock(64, 4);
        hipLaunchKernelGGL(transpose_cl, tgrid, tblock, 0, stream, images, tl);

        dim3 grid(K * PH);
        dim3 block(64, 4);
        hipLaunchKernelGGL(roi_align_sep, grid, block, 0, stream, tl, rois, out);
    } else {
        dim3 grid(K * PH);
        dim3 block(PW, 4);
        hipLaunchKernelGGL(roi_align_fallback, grid, block, 0, stream,
                           images, rois, out);
    }
}